// Round 6
// baseline (684.146 us; speedup 1.0000x reference)
//
#include <hip/hip_runtime.h>
#include <hip/hip_bf16.h>

typedef unsigned char u8;
typedef unsigned short u16;
typedef unsigned int u32;
typedef int i32x4 __attribute__((ext_vector_type(4)));
typedef int i32x8 __attribute__((ext_vector_type(8)));
typedef float f32x16 __attribute__((ext_vector_type(16)));

#define HD 2880          // H == I == 2880
#define GUN 5760         // 2*I
#define NEXP 8
#define NTOK 1024
#define NASSIGN 4096     // T*K
#define MAXPAD 5120      // padded routed rows
#define MAXTILES 40
#define SROWS 90         // 2880/32
#define RB 1440          // packed fp4 row bytes (2880/2)
#define SB 96            // padded scale row bytes (90 -> 96)

// ---------------- global -> LDS direct staging (16B per lane) ----------------
__device__ __forceinline__ void gll16(const void* g, void* l) {
  __builtin_amdgcn_global_load_lds(
      (const __attribute__((address_space(1))) u32*)g,
      (__attribute__((address_space(3))) u32*)l, 16, 0, 0);
}

__device__ __forceinline__ i32x8 to8(i32x4 v) {
  i32x8 r;
  r[0] = v[0]; r[1] = v[1]; r[2] = v[2]; r[3] = v[3];
  r[4] = 0; r[5] = 0; r[6] = 0; r[7] = 0;
  return r;
}

// ---------------- exact mxfp4 code helpers ----------------
// code = e2m1 nibble replicating LEVELS[searchsorted(MIDS, x)] exactly
__device__ __forceinline__ int quant_code(float v, float inv) {
  float x = v * inv;
  float a = fabsf(x);
  int n;
  if (x > 0.f)
    n = (a > 0.25f) + (a > 0.75f) + (a > 1.25f) + (a > 1.75f) +
        (a > 2.5f)  + (a > 3.5f)  + (a > 5.f);
  else
    n = (a >= 0.25f) + (a >= 0.75f) + (a >= 1.25f) + (a >= 1.75f) +
        (a >= 2.5f)  + (a >= 3.5f)  + (a >= 5.f);
  return x < 0.f ? (8 | n) : n;   // x==0 -> n==0 -> code 0
}

// ---------------- routing ----------------
__global__ __launch_bounds__(256)
void route_k(const int* __restrict__ ridx, const float* __restrict__ rw,
             int* __restrict__ tt_e, int* __restrict__ tt_row0, int* __restrict__ tt_rows,
             int* __restrict__ atok, int* __restrict__ tok2row) {
  __shared__ int cnt[NEXP], cur[NEXP], poff[NEXP];
  int tid = threadIdx.x;
  if (tid < NEXP) { cnt[tid] = 0; cur[tid] = 0; }
  __syncthreads();
  for (int a = tid; a < NASSIGN; a += 256) atomicAdd(&cnt[ridx[a]], 1);
  __syncthreads();
  if (tid == 0) {
    int off = 0, nt = 0;
    for (int e = 0; e < NEXP; ++e) {
      poff[e] = off;
      int cc = cnt[e];
      int ntl = (cc + 127) >> 7;
      for (int i = 0; i < ntl; ++i) {
        int rem = cc - i * 128;
        tt_e[nt] = e; tt_row0[nt] = off + i * 128; tt_rows[nt] = rem < 128 ? rem : 128;
        ++nt;
      }
      off += ntl * 128;
    }
    for (; nt < 64; ++nt) { tt_e[nt] = 0; tt_row0[nt] = 0; tt_rows[nt] = 0; }
  }
  __syncthreads();
  for (int r2 = tid; r2 < MAXPAD; r2 += 256) atok[r2] = 0;
  __syncthreads();
  for (int a = tid; a < NASSIGN; a += 256) {
    int e = ridx[a];
    int p = atomicAdd(&cur[e], 1);
    int r2 = poff[e] + p;
    atok[r2] = a >> 2;
    tok2row[a] = r2;
  }
}

// ---------------- activation quant: x -> packed fp4 + e8m0 scales ----------------
__global__ __launch_bounds__(384)
void quant_x_k(const float* __restrict__ x, u8* __restrict__ xqp, u8* __restrict__ xs) {
  int t = blockIdx.x;
  int tid = threadIdx.x;
  if (tid >= 360) return;       // 360*8 = 2880
  const float* xp = x + (long)t * HD + tid * 8;
  float4 v0 = *reinterpret_cast<const float4*>(xp);
  float4 v1 = *reinterpret_cast<const float4*>(xp + 4);
  float vv[8] = {v0.x, v0.y, v0.z, v0.w, v1.x, v1.y, v1.z, v1.w};
  float am = 0.f;
#pragma unroll
  for (int j = 0; j < 8; ++j) am = fmaxf(am, fabsf(vv[j]));
  am = fmaxf(am, __shfl_xor(am, 1));
  am = fmaxf(am, __shfl_xor(am, 2));
  u32 eb = (__float_as_uint(am) >> 23) & 255u;
  float inv = __uint_as_float((256u - eb) << 23);
  u32 w = 0;
#pragma unroll
  for (int j = 0; j < 8; ++j) {
    u32 c = (am > 0.f) ? (u32)quant_code(vv[j], inv) : 0u;
    w |= c << (4 * j);          // low nibble = even k
  }
  *reinterpret_cast<u32*>(xqp + (long)t * RB + tid * 4) = w;
  if ((tid & 3) == 0)
    xs[(long)t * SB + (tid >> 2)] = (u8)(am > 0.f ? (eb - 2u) : 0u);
}

// ---------------- weight repack: int32 codes [e][h][f] -> packed fp4 wq[e][f][h/2] ----
__global__ __launch_bounds__(320)
void repack_k(const int* __restrict__ codes, u8* __restrict__ wq, int ND) {
  __shared__ uint4 lt[80][4];
  const int tid = threadIdx.x;
  const int fl = tid % 80, hql = tid / 80;
  const int f0 = blockIdx.x * 80;
  const int hbq = blockIdx.y;
  const int e = blockIdx.z;
  const int hb = hbq * 4 + hql;
  if (hb < SROWS) {
    const long cbase = ((long)e * HD + hb * 32) * ND + f0 + fl;
    u32 w[4] = {0, 0, 0, 0};
#pragma unroll
    for (int j = 0; j < 16; ++j) {
      u32 c0 = (u32)codes[cbase + (long)(2 * j) * ND] & 15u;
      u32 c1 = (u32)codes[cbase + (long)(2 * j + 1) * ND] & 15u;
      w[j >> 2] |= (c0 | (c1 << 4)) << ((j & 3) * 8);
    }
    lt[fl][hql] = make_uint4(w[0], w[1], w[2], w[3]);
  }
  __syncthreads();
  const int row = tid >> 2, part = tid & 3;
  const int hbw = hbq * 4 + part;
  if (hbw < SROWS)
    *reinterpret_cast<uint4*>(wq + ((long)e * ND + f0 + row) * RB + hbw * 16) = lt[row][part];
}

// ---------------- scale repack: int32 scales [e][90][f] -> e8m0 wsb[e][f][96] ----
__global__ __launch_bounds__(384)
void srepack_k(const int* __restrict__ scales, u8* __restrict__ wsb, int ND) {
  const int tid = threadIdx.x;
  const int fl = tid / 6, p = tid % 6;
  const int f = blockIdx.x * 64 + fl;
  const int e = blockIdx.y;
  u32 w[4] = {0, 0, 0, 0};
#pragma unroll
  for (int j = 0; j < 16; ++j) {
    int t = p * 16 + j;
    u32 b = (t < SROWS) ? (u32)(scales[((long)e * SROWS + t) * ND + f] + 115) & 255u : 0u;
    w[j >> 2] |= b << ((j & 3) * 8);
  }
  *reinterpret_cast<uint4*>(wsb + ((long)e * ND + f) * SB + p * 16) =
      make_uint4(w[0], w[1], w[2], w[3]);
}

// ---------------- MX-fp4 MFMA GEMM ----------------
// BM=128, BN=192, BK=192 (15 phases, 12 mfma/phase/thread). 384 thr = 6 waves
// (2m x 3n). B in LDS [sub(6)][col(192)][16B] (frag reads lane-contiguous,
// conflict-free); A per-lane direct from L2-resident packed buffer with
// one-phase register prefetch. Counted vmcnt(3): next-phase B stays in flight.
template<bool IS_GU>
__global__ __launch_bounds__(384, 3)
void moe_gemm(const u8* __restrict__ Apay, const u8* __restrict__ Ascl,
              const u8* __restrict__ wq, const u8* __restrict__ wsb,
              const float* __restrict__ bias,
              const int* __restrict__ tt_e, const int* __restrict__ tt_row0,
              const int* __restrict__ tt_rows, const int* __restrict__ atok,
              u8* __restrict__ gqp, u8* __restrict__ gs,
              float* __restrict__ partial) {
  constexpr int ND = IS_GU ? GUN : HD;
  constexpr int BN = 192;
  constexpr int KS = 15;             // 2880 / 192
  constexpr int BT = BN * 6;         // 16B chunks per phase-tile (1152)

  // XCD-chunked bijective swizzle, m-tile fastest (B-panel L2 reuse)
  int nb = gridDim.x * gridDim.y;
  int lin = blockIdx.x + gridDim.x * blockIdx.y;
  int q_ = nb >> 3, r_ = nb & 7;
  int xcd = lin & 7, pos = lin >> 3;
  int L = (xcd < r_ ? xcd * (q_ + 1) : r_ * (q_ + 1) + (xcd - r_) * q_) + pos;
  int mt = L % (int)gridDim.x;
  int nt = L / (int)gridDim.x;

  const int rows = tt_rows[mt];
  if (rows <= 0) return;
  const int e = tt_e[mt];
  const int row0 = tt_row0[mt];
  const int tid = threadIdx.x;
  const int lane = tid & 63;
  const int wid = tid >> 6;
  const int wm = wid & 1;            // 2 row-waves (64 rows each)
  const int wn = wid >> 1;           // 3 col-waves (64 cols each)
  const int ml = lane & 31;
  const int kc = lane >> 5;

  __shared__ __align__(16) u8 Bb[2][BT * 16];   // 18KB x2
  __shared__ u8 ASl[SB * 128];                  // [kb][row]
  __shared__ u8 BSl[SB * BN];                   // [kb][col]
  __shared__ __align__(16) u8 Glds[IS_GU ? 128 * 48 : 16];

  // ---- B staging sources: thread stages slots tid, tid+384, tid+768 ----
  const u8* bsrc[3];
#pragma unroll
  for (int i = 0; i < 3; ++i) {
    int s = tid + i * 384;
    int cc = s / BN, col = s % BN;
    bsrc[i] = wq + ((long)e * ND + (long)nt * BN + col) * RB + cc * 16;
  }

  // ---- A row base pointers (per-lane direct loads) ----
  const u8* pA[2];
#pragma unroll
  for (int mf = 0; mf < 2; ++mf) {
    int rowg = row0 + wm * 64 + mf * 32 + ml;
    long rbase = IS_GU ? (long)atok[rowg] * RB : (long)rowg * RB;
    pA[mf] = Apay + rbase;
  }

  // ---- one-time scale staging, [kb][row/col] ----
  for (int sc = tid; sc < 768; sc += 384) {
    int row = sc / 6, part = sc % 6;
    long rbase = IS_GU ? (long)atok[row0 + row] * SB : (long)(row0 + row) * SB;
    uint4 v = *reinterpret_cast<const uint4*>(Ascl + rbase + part * 16);
    u32 arr[4] = {v.x, v.y, v.z, v.w};
#pragma unroll
    for (int j = 0; j < 16; ++j)
      ASl[(part * 16 + j) * 128 + row] = (u8)(arr[j >> 2] >> ((j & 3) * 8));
  }
  for (int sc = tid; sc < BN * 6; sc += 384) {
    int col = sc / 6, part = sc % 6;
    uint4 v = *reinterpret_cast<const uint4*>(
        wsb + ((long)e * ND + (long)nt * BN + col) * SB + part * 16);
    u32 arr[4] = {v.x, v.y, v.z, v.w};
#pragma unroll
    for (int j = 0; j < 16; ++j)
      BSl[(part * 16 + j) * BN + col] = (u8)(arr[j >> 2] >> ((j & 3) * 8));
  }

  auto stage = [&](int buf, int ks) {
#pragma unroll
    for (int i = 0; i < 3; ++i)
      gll16(bsrc[i] + ks * 96, &Bb[buf][(tid + i * 384) * 16]);
  };

  stage(0, 0);
  i32x4 av[2][3];
#pragma unroll
  for (int mf = 0; mf < 2; ++mf)
#pragma unroll
    for (int t = 0; t < 3; ++t)
      av[mf][t] = *reinterpret_cast<const i32x4*>(pA[mf] + t * 32 + kc * 16);

  __syncthreads();   // scales in LDS + tile 0 drained (full waitcnt)

  f32x16 acc[2][2];
#pragma unroll
  for (int a_ = 0; a_ < 2; ++a_)
#pragma unroll
    for (int b_ = 0; b_ < 2; ++b_)
#pragma unroll
      for (int k_ = 0; k_ < 16; ++k_) acc[a_][b_][k_] = 0.f;

  for (int ks = 0; ks < KS; ++ks) {
    const int cur = ks & 1;
    if (ks + 1 < KS) {
      stage(cur ^ 1, ks + 1);
      // steady state outstanding <= [stage(ks),av(ks),stage(ks+1)] = 12;
      // vmcnt(3) guarantees stage(ks)+av(ks) done under ANY issue order,
      // keeps (at most) stage(ks+1) in flight.
      asm volatile("s_waitcnt vmcnt(3)" ::: "memory");
    } else {
      asm volatile("s_waitcnt vmcnt(0)" ::: "memory");
    }
    __builtin_amdgcn_s_barrier();
    __builtin_amdgcn_sched_barrier(0);

#pragma unroll
    for (int t = 0; t < 3; ++t) {
      const int sub = 2 * t + kc;
      const int kb = 6 * ks + sub;
#pragma unroll
      for (int nf = 0; nf < 2; ++nf) {
        const int bcol = wn * 64 + nf * 32 + ml;
        i32x4 bv = *reinterpret_cast<const i32x4*>(&Bb[cur][(sub * BN + bcol) * 16]);
        int sb = (int)BSl[kb * BN + bcol];
        i32x8 b8 = to8(bv);
#pragma unroll
        for (int mf = 0; mf < 2; ++mf) {
          int sa = (int)ASl[kb * 128 + wm * 64 + mf * 32 + ml];
          acc[mf][nf] = __builtin_amdgcn_mfma_scale_f32_32x32x64_f8f6f4(
              to8(av[mf][t]), b8, acc[mf][nf], 4, 4, 0, sa, 0, sb);
        }
      }
    }

    if (ks + 1 < KS) {
#pragma unroll
      for (int mf = 0; mf < 2; ++mf)
#pragma unroll
        for (int t = 0; t < 3; ++t)
          av[mf][t] = *reinterpret_cast<const i32x4*>(
              pA[mf] + (ks + 1) * 96 + t * 32 + kc * 16);
    }
    __builtin_amdgcn_sched_barrier(0);
    __builtin_amdgcn_s_barrier();     // reads done before buffer reuse
  }

  // ---- epilogues ----
  const int hlf = lane >> 5;
  if constexpr (IS_GU) {
    bool evenl = ((lane & 1) == 0);
#pragma unroll
    for (int mf = 0; mf < 2; ++mf) {
      float gated[2][16];
#pragma unroll
      for (int nf = 0; nf < 2; ++nf) {
        int fgc = nt * BN + wn * 64 + nf * 32 + ml;
        float bown = bias[e * GUN + fgc];
#pragma unroll
        for (int rr = 0; rr < 16; ++rr) {
          float z = acc[mf][nf][rr] + bown;
          float zp = __shfl_xor(z, 1);
          float g = evenl ? z : zp;
          float u = evenl ? zp : z;
          g = fminf(g, 7.f);
          u = fminf(fmaxf(u, -7.f), 7.f);
          float sg = 1.f / (1.f + expf(-1.702f * g));
          gated[nf][rr] = (u + 1.f) * (g * sg);
        }
      }
#pragma unroll
      for (int rr = 0; rr < 16; ++rr) {
        float am = fmaxf(fabsf(gated[0][rr]), fabsf(gated[1][rr]));
        am = fmaxf(am, __shfl_xor(am, 2));
        am = fmaxf(am, __shfl_xor(am, 4));
        am = fmaxf(am, __shfl_xor(am, 8));
        am = fmaxf(am, __shfl_xor(am, 16));
        u32 eb = (__float_as_uint(am) >> 23) & 255u;
        float inv = __uint_as_float((256u - eb) << 23);
        int c0 = (am > 0.f) ? quant_code(gated[0][rr], inv) : 0;
        int c1 = (am > 0.f) ? quant_code(gated[1][rr], inv) : 0;
        int b0 = c0 | (__shfl_xor(c0, 2) << 4);   // valid at (lane&3)==0
        int b1 = c1 | (__shfl_xor(c1, 2) << 4);
        int mrow = (rr & 3) + 8 * (rr >> 2) + 4 * hlf;
        int rloc = wm * 64 + mf * 32 + mrow;
        if ((lane & 3) == 0) {
          Glds[rloc * 48 + wn * 16 + (ml >> 2)] = (u8)b0;
          Glds[rloc * 48 + wn * 16 + 8 + (ml >> 2)] = (u8)b1;
          if (rloc < rows && ml == 0)
            gs[(long)(row0 + rloc) * SB + nt * 3 + wn] = (u8)(am > 0.f ? (eb - 2u) : 0u);
        }
      }
    }
    __syncthreads();
    // coalesced 16B stores of the packed tile
    {
      int row = tid / 3, part = tid % 3;
      uint4 v = *reinterpret_cast<const uint4*>(&Glds[row * 48 + part * 16]);
      *reinterpret_cast<uint4*>(gqp + (long)(row0 + row) * RB + nt * 48 + part * 16) = v;
    }
  } else {
#pragma unroll
    for (int mf = 0; mf < 2; ++mf) {
#pragma unroll
      for (int rr = 0; rr < 16; ++rr) {
        int mrow = (rr & 3) + 8 * (rr >> 2) + 4 * hlf;
        int rloc = wm * 64 + mf * 32 + mrow;
        if (rloc >= rows) continue;
        long rg = row0 + rloc;
#pragma unroll
        for (int nf = 0; nf < 2; ++nf) {
          int hg = nt * BN + wn * 64 + nf * 32 + ml;
          partial[rg * HD + hg] = acc[mf][nf][rr] + bias[e * HD + hg];
        }
      }
    }
  }
}

// ---------------- final combine: out[t] = sum_k rw[t,k] * partial[row(t,k)] ----
__global__ __launch_bounds__(768)
void gather_k(const float* __restrict__ partial, const int* __restrict__ tok2row,
              const float* __restrict__ rw, float* __restrict__ out) {
  int t = blockIdx.x;
  int i = threadIdx.x;
  if (i >= 720) return;            // 720*4 = 2880
  int c = i * 4;
  float4 s = make_float4(0.f, 0.f, 0.f, 0.f);
#pragma unroll
  for (int k = 0; k < 4; ++k) {
    int r = tok2row[t * 4 + k];
    float w = rw[t * 4 + k];
    float4 v = *reinterpret_cast<const float4*>(&partial[(long)r * HD + c]);
    s.x += w * v.x; s.y += w * v.y; s.z += w * v.z; s.w += w * v.w;
  }
  *reinterpret_cast<float4*>(&out[(long)t * HD + c]) = s;
}

// ---------------- launcher ----------------
extern "C" void kernel_launch(void* const* d_in, const int* in_sizes, int n_in,
                              void* d_out, int out_size, void* d_ws, size_t ws_size,
                              hipStream_t stream) {
  (void)in_sizes; (void)n_in; (void)ws_size; (void)out_size;
  const float* x   = (const float*)d_in[0];
  const int* ridx  = (const int*)d_in[1];
  const float* rw  = (const float*)d_in[2];
  const int* guc   = (const int*)d_in[3];
  const int* gus   = (const int*)d_in[4];
  const float* gub = (const float*)d_in[5];
  const int* dnc   = (const int*)d_in[6];
  const int* dns   = (const int*)d_in[7];
  const float* dnb = (const float*)d_in[8];
  float* out = (float*)d_out;
  char* ws = (char*)d_ws;

  // ws layout (~175 MB)
  int* tt_e    = (int*)(ws);
  int* tt_row0 = (int*)(ws + 1024);
  int* tt_rows = (int*)(ws + 2048);
  int* atok    = (int*)(ws + 4096);
  int* tok2row = (int*)(ws + 4096 + MAXPAD * 4);
  size_t off = 65536;
  u8* xqp = (u8*)(ws + off);  off += (size_t)NTOK * RB;       // 1.47 MB
  u8* xs  = (u8*)(ws + off);  off += (size_t)NTOK * SB;       // 98 KB
  u8* gqp = (u8*)(ws + off);  off += (size_t)MAXPAD * RB;     // 7.37 MB
  u8* gs  = (u8*)(ws + off);  off += (size_t)MAXPAD * SB;     // 0.49 MB
  u8* wqg = (u8*)(ws + off);  off += (size_t)NEXP * GUN * RB; // 66.4 MB
  u8* wsg = (u8*)(ws + off);  off += (size_t)NEXP * GUN * SB; // 4.4 MB
  u8* wqd = (u8*)(ws + off);  off += (size_t)NEXP * HD * RB;  // 33.2 MB
  u8* wsd = (u8*)(ws + off);  off += (size_t)NEXP * HD * SB;  // 2.2 MB
  float* partial = (float*)(ws + off); off += (size_t)MAXPAD * HD * 4; // 59 MB

  route_k<<<1, 256, 0, stream>>>(ridx, rw, tt_e, tt_row0, tt_rows, atok, tok2row);
  quant_x_k<<<NTOK, 384, 0, stream>>>(x, xqp, xs);
  repack_k<<<dim3(GUN / 80, 23, NEXP), 320, 0, stream>>>(guc, wqg, GUN);
  srepack_k<<<dim3(GUN / 64, NEXP), 384, 0, stream>>>(gus, wsg, GUN);
  repack_k<<<dim3(HD / 80, 23, NEXP), 320, 0, stream>>>(dnc, wqd, HD);
  srepack_k<<<dim3(HD / 64, NEXP), 384, 0, stream>>>(dns, wsd, HD);
  moe_gemm<true><<<dim3(MAXTILES, 30), 384, 0, stream>>>(
      xqp, xs, wqg, wsg, gub, tt_e, tt_row0, tt_rows, atok, gqp, gs, nullptr);
  moe_gemm<false><<<dim3(MAXTILES, 15), 384, 0, stream>>>(
      gqp, gs, wqd, wsd, dnb, tt_e, tt_row0, tt_rows, atok, nullptr, nullptr, partial);
  gather_k<<<NTOK, 768, 0, stream>>>(partial, tok2row, rw, out);
}

// Round 7
// 683.983 us; speedup vs baseline: 1.0002x; 1.0002x over previous
//
#include <hip/hip_runtime.h>
#include <hip/hip_bf16.h>

typedef unsigned char u8;
typedef unsigned short u16;
typedef unsigned int u32;
typedef int i32x4 __attribute__((ext_vector_type(4)));
typedef int i32x8 __attribute__((ext_vector_type(8)));
typedef float f32x16 __attribute__((ext_vector_type(16)));

#define HD 2880          // H == I == 2880
#define GUN 5760         // 2*I
#define NEXP 8
#define NTOK 1024
#define NASSIGN 4096     // T*K
#define MAXPAD 5120      // padded routed rows
#define MAXTILES 40
#define SROWS 90         // 2880/32
#define RB 1440          // packed fp4 row bytes (2880/2)
#define SB 96            // padded scale row bytes (90 -> 96)

// ---------------- global -> LDS direct staging (16B per lane) ----------------
__device__ __forceinline__ void gll16(const void* g, void* l) {
  __builtin_amdgcn_global_load_lds(
      (const __attribute__((address_space(1))) u32*)g,
      (__attribute__((address_space(3))) u32*)l, 16, 0, 0);
}

// i32x4 -> i32x8 with UNDEF high half (fp4 MFMA reads only regs 0-3; avoids movs)
__device__ __forceinline__ i32x8 ext8(i32x4 v) {
  return __builtin_shufflevector(v, v, 0, 1, 2, 3, -1, -1, -1, -1);
}

// ---------------- exact mxfp4 code helpers ----------------
// code = e2m1 nibble replicating LEVELS[searchsorted(MIDS, x)] exactly
__device__ __forceinline__ int quant_code(float v, float inv) {
  float x = v * inv;
  float a = fabsf(x);
  int n;
  if (x > 0.f)
    n = (a > 0.25f) + (a > 0.75f) + (a > 1.25f) + (a > 1.75f) +
        (a > 2.5f)  + (a > 3.5f)  + (a > 5.f);
  else
    n = (a >= 0.25f) + (a >= 0.75f) + (a >= 1.25f) + (a >= 1.75f) +
        (a >= 2.5f)  + (a >= 3.5f)  + (a >= 5.f);
  return x < 0.f ? (8 | n) : n;   // x==0 -> n==0 -> code 0
}

// ---------------- routing ----------------
__global__ __launch_bounds__(256)
void route_k(const int* __restrict__ ridx, const float* __restrict__ rw,
             int* __restrict__ tt_e, int* __restrict__ tt_row0, int* __restrict__ tt_rows,
             int* __restrict__ atok, int* __restrict__ tok2row) {
  __shared__ int cnt[NEXP], cur[NEXP], poff[NEXP];
  int tid = threadIdx.x;
  if (tid < NEXP) { cnt[tid] = 0; cur[tid] = 0; }
  __syncthreads();
  for (int a = tid; a < NASSIGN; a += 256) atomicAdd(&cnt[ridx[a]], 1);
  __syncthreads();
  if (tid == 0) {
    int off = 0, nt = 0;
    for (int e = 0; e < NEXP; ++e) {
      poff[e] = off;
      int cc = cnt[e];
      int ntl = (cc + 127) >> 7;
      for (int i = 0; i < ntl; ++i) {
        int rem = cc - i * 128;
        tt_e[nt] = e; tt_row0[nt] = off + i * 128; tt_rows[nt] = rem < 128 ? rem : 128;
        ++nt;
      }
      off += ntl * 128;
    }
    for (; nt < 64; ++nt) { tt_e[nt] = 0; tt_row0[nt] = 0; tt_rows[nt] = 0; }
  }
  __syncthreads();
  for (int r2 = tid; r2 < MAXPAD; r2 += 256) atok[r2] = 0;
  __syncthreads();
  for (int a = tid; a < NASSIGN; a += 256) {
    int e = ridx[a];
    int p = atomicAdd(&cur[e], 1);
    int r2 = poff[e] + p;
    atok[r2] = a >> 2;
    tok2row[a] = r2;
  }
}

// ---------------- activation quant: x -> packed fp4 + e8m0 scales ----------------
__global__ __launch_bounds__(384)
void quant_x_k(const float* __restrict__ x, u8* __restrict__ xqp, u8* __restrict__ xs) {
  int t = blockIdx.x;
  int tid = threadIdx.x;
  if (tid >= 360) return;       // 360*8 = 2880
  const float* xp = x + (long)t * HD + tid * 8;
  float4 v0 = *reinterpret_cast<const float4*>(xp);
  float4 v1 = *reinterpret_cast<const float4*>(xp + 4);
  float vv[8] = {v0.x, v0.y, v0.z, v0.w, v1.x, v1.y, v1.z, v1.w};
  float am = 0.f;
#pragma unroll
  for (int j = 0; j < 8; ++j) am = fmaxf(am, fabsf(vv[j]));
  am = fmaxf(am, __shfl_xor(am, 1));
  am = fmaxf(am, __shfl_xor(am, 2));
  u32 eb = (__float_as_uint(am) >> 23) & 255u;
  float inv = __uint_as_float((256u - eb) << 23);
  u32 w = 0;
#pragma unroll
  for (int j = 0; j < 8; ++j) {
    u32 c = (am > 0.f) ? (u32)quant_code(vv[j], inv) : 0u;
    w |= c << (4 * j);          // low nibble = even k
  }
  *reinterpret_cast<u32*>(xqp + (long)t * RB + tid * 4) = w;
  if ((tid & 3) == 0)
    xs[(long)t * SB + (tid >> 2)] = (u8)(am > 0.f ? (eb - 2u) : 0u);
}

// ---------------- weight repack: int32 codes [e][h][f] -> packed fp4 wq[e][f][h/2] ----
__global__ __launch_bounds__(320)
void repack_k(const int* __restrict__ codes, u8* __restrict__ wq, int ND) {
  __shared__ uint4 lt[80][4];
  const int tid = threadIdx.x;
  const int fl = tid % 80, hql = tid / 80;
  const int f0 = blockIdx.x * 80;
  const int hbq = blockIdx.y;
  const int e = blockIdx.z;
  const int hb = hbq * 4 + hql;
  if (hb < SROWS) {
    const long cbase = ((long)e * HD + hb * 32) * ND + f0 + fl;
    u32 w[4] = {0, 0, 0, 0};
#pragma unroll
    for (int j = 0; j < 16; ++j) {
      u32 c0 = (u32)codes[cbase + (long)(2 * j) * ND] & 15u;
      u32 c1 = (u32)codes[cbase + (long)(2 * j + 1) * ND] & 15u;
      w[j >> 2] |= (c0 | (c1 << 4)) << ((j & 3) * 8);
    }
    lt[fl][hql] = make_uint4(w[0], w[1], w[2], w[3]);
  }
  __syncthreads();
  const int row = tid >> 2, part = tid & 3;
  const int hbw = hbq * 4 + part;
  if (hbw < SROWS)
    *reinterpret_cast<uint4*>(wq + ((long)e * ND + f0 + row) * RB + hbw * 16) = lt[row][part];
}

// ---------------- scale repack: int32 scales [e][90][f] -> e8m0 wsb[e][f][96] ----
__global__ __launch_bounds__(384)
void srepack_k(const int* __restrict__ scales, u8* __restrict__ wsb, int ND) {
  const int tid = threadIdx.x;
  const int fl = tid / 6, p = tid % 6;
  const int f = blockIdx.x * 64 + fl;
  const int e = blockIdx.y;
  u32 w[4] = {0, 0, 0, 0};
#pragma unroll
  for (int j = 0; j < 16; ++j) {
    int t = p * 16 + j;
    u32 b = (t < SROWS) ? (u32)(scales[((long)e * SROWS + t) * ND + f] + 115) & 255u : 0u;
    w[j >> 2] |= b << ((j & 3) * 8);
  }
  *reinterpret_cast<uint4*>(wsb + ((long)e * ND + f) * SB + p * 16) =
      make_uint4(w[0], w[1], w[2], w[3]);
}

// ---------------- MX-fp4 MFMA GEMM ----------------
// BM=128, BN=192, BK=64. 384 thr = 6 waves (2m x 3n), wave tile 64x64,
// MF=NF=2 (4 mfma / 4 LDS-frag-reads per thread-phase). A AND B staged via
// global_load_lds (coalesced), [kc][row][16B] layout, double-buffered with
// per-wave counted vmcnt ({2,2,2,2,1,1} chunks -> vmcnt(2)/(1)).
template<bool IS_GU>
__global__ __launch_bounds__(384, 3)
void moe_gemm(const u8* __restrict__ Apay, const u8* __restrict__ Ascl,
              const u8* __restrict__ wq, const u8* __restrict__ wsb,
              const float* __restrict__ bias,
              const int* __restrict__ tt_e, const int* __restrict__ tt_row0,
              const int* __restrict__ tt_rows, const int* __restrict__ atok,
              u8* __restrict__ gqp, u8* __restrict__ gs,
              float* __restrict__ partial) {
  constexpr int ND = IS_GU ? GUN : HD;
  constexpr int BN = 192;
  constexpr int KS = 45;

  // XCD-chunked bijective swizzle, m-tile fastest (B-panel L2 reuse)
  int nb = gridDim.x * gridDim.y;
  int lin = blockIdx.x + gridDim.x * blockIdx.y;
  int q_ = nb >> 3, r_ = nb & 7;
  int xcd = lin & 7, pos = lin >> 3;
  int L = (xcd < r_ ? xcd * (q_ + 1) : r_ * (q_ + 1) + (xcd - r_) * q_) + pos;
  int mt = L % (int)gridDim.x;
  int nt = L / (int)gridDim.x;

  const int rows = tt_rows[mt];
  if (rows <= 0) return;
  const int e = tt_e[mt];
  const int row0 = tt_row0[mt];
  const int tid = threadIdx.x;
  const int lane = tid & 63;
  const int wid = tid >> 6;
  const int wm = wid & 1;            // 2 m-waves, span 64
  const int wn = wid >> 1;           // 3 n-waves, span 64
  const int ml = lane & 31;
  const int kc = lane >> 5;

  // A region: [kc(2)][row(128)][16B] = 4KB; B region: [kc(2)][col(192)][16B] = 6KB
  __shared__ __align__(16) u8 Tiles[2][10240];
  __shared__ u8 ASl[96 * 128];       // [kb][row]
  __shared__ u8 BSl[96 * 192];       // [kb][col]

  // ---- staging chunk assignment: 640 chunks = 10 wave-instrs {2,2,2,2,1,1} ----
  const int NI = (wid < 4) ? 2 : 1;
  const int cbase = (wid < 4) ? wid * 128 : 512 + (wid - 4) * 64;
  const u8* csrc[2];
  int cdst[2];
#pragma unroll
  for (int i = 0; i < 2; ++i) {
    int c = cbase + i * 64 + lane;   // i < NI only used
    if (i < NI) {
      if (c < 256) {                 // A chunk: [kc][row]
        int row = c & 127, k2 = c >> 7;
        long rb = IS_GU ? (long)atok[row0 + row] * RB : (long)(row0 + row) * RB;
        csrc[i] = Apay + rb + k2 * 16;
      } else {                       // B chunk: [kc][col]
        int q = c - 256;
        int k2 = q >= 192;
        int col = q - k2 * 192;
        csrc[i] = wq + ((long)e * ND + (long)nt * BN + col) * RB + k2 * 16;
      }
      cdst[i] = c * 16;
    } else { csrc[i] = Apay; cdst[i] = 0; }
  }

  auto stage = [&](int buf, int ks) {
#pragma unroll
    for (int i = 0; i < 2; ++i)
      if (i < NI) gll16(csrc[i] + ks * 32, &Tiles[buf][cdst[i]]);
  };

  stage(0, 0);   // prologue: tile 0 in flight

  // ---- one-time scale staging: ASl [kb][row], BSl [kb][col] ----
  for (int sc = tid; sc < 768; sc += 384) {
    int row = sc / 6, part = sc % 6;
    long rb = IS_GU ? (long)atok[row0 + row] * SB : (long)(row0 + row) * SB;
    uint4 v = *reinterpret_cast<const uint4*>(Ascl + rb + part * 16);
    u32 arr[4] = {v.x, v.y, v.z, v.w};
#pragma unroll
    for (int j = 0; j < 16; ++j)
      ASl[(part * 16 + j) * 128 + row] = (u8)(arr[j >> 2] >> ((j & 3) * 8));
  }
  for (int sc = tid; sc < 1152; sc += 384) {
    int col = sc / 6, part = sc % 6;
    uint4 v = *reinterpret_cast<const uint4*>(
        wsb + ((long)e * ND + (long)nt * BN + col) * SB + part * 16);
    u32 arr[4] = {v.x, v.y, v.z, v.w};
#pragma unroll
    for (int j = 0; j < 16; ++j)
      BSl[(part * 16 + j) * 192 + col] = (u8)(arr[j >> 2] >> ((j & 3) * 8));
  }

  __syncthreads();   // scales staged + tile 0 drained (compiler full waitcnt)

  f32x16 acc[2][2];
#pragma unroll
  for (int a_ = 0; a_ < 2; ++a_)
#pragma unroll
    for (int b_ = 0; b_ < 2; ++b_)
#pragma unroll
      for (int k_ = 0; k_ < 16; ++k_) acc[a_][b_][k_] = 0.f;

  const int arow0 = wm * 64;
  const int bcol0 = wn * 64;

  for (int ks = 0; ks < KS; ++ks) {
    const int cur = ks & 1;
    if (ks + 1 < KS) {
      stage(cur ^ 1, ks + 1);            // next tile: stays in flight
      if (wid < 4) asm volatile("s_waitcnt vmcnt(2)" ::: "memory");
      else         asm volatile("s_waitcnt vmcnt(1)" ::: "memory");
    } else {
      asm volatile("s_waitcnt vmcnt(0)" ::: "memory");
    }
    __builtin_amdgcn_s_barrier();        // current tile staged on all waves
    __builtin_amdgcn_sched_barrier(0);

    const u8* T = Tiles[cur];
    const int kb = 2 * ks + kc;
    i32x4 af[2], bf[2];
    int sa[2], sb[2];
#pragma unroll
    for (int mf = 0; mf < 2; ++mf) {
      int row = arow0 + mf * 32 + ml;
      af[mf] = *reinterpret_cast<const i32x4*>(&T[(kc * 128 + row) * 16]);
      sa[mf] = (int)ASl[kb * 128 + row];
    }
#pragma unroll
    for (int nf = 0; nf < 2; ++nf) {
      int col = bcol0 + nf * 32 + ml;
      bf[nf] = *reinterpret_cast<const i32x4*>(&T[4096 + (kc * 192 + col) * 16]);
      sb[nf] = (int)BSl[kb * 192 + col];
    }
    __builtin_amdgcn_s_setprio(1);
#pragma unroll
    for (int mf = 0; mf < 2; ++mf)
#pragma unroll
      for (int nf = 0; nf < 2; ++nf)
        acc[mf][nf] = __builtin_amdgcn_mfma_scale_f32_32x32x64_f8f6f4(
            ext8(af[mf]), ext8(bf[nf]), acc[mf][nf], 4, 4, 0, sa[mf], 0, sb[nf]);
    __builtin_amdgcn_s_setprio(0);

    __builtin_amdgcn_sched_barrier(0);
    __builtin_amdgcn_s_barrier();        // reads done before buffer reuse
  }

  // ---- epilogues (geometry identical to verified round-6: wm span 64, wn span 64) ----
  const int hlf = lane >> 5;
  if constexpr (IS_GU) {
    u8* Glds = &Tiles[0][0];             // 128 x 48 bytes, overlaid on Tiles
    bool evenl = ((lane & 1) == 0);
#pragma unroll
    for (int mf = 0; mf < 2; ++mf) {
      float gated[2][16];
#pragma unroll
      for (int nf = 0; nf < 2; ++nf) {
        int fgc = nt * BN + wn * 64 + nf * 32 + ml;
        float bown = bias[e * GUN + fgc];
#pragma unroll
        for (int rr = 0; rr < 16; ++rr) {
          float z = acc[mf][nf][rr] + bown;
          float zp = __shfl_xor(z, 1);
          float g = evenl ? z : zp;
          float u = evenl ? zp : z;
          g = fminf(g, 7.f);
          u = fminf(fmaxf(u, -7.f), 7.f);
          float sg = 1.f / (1.f + expf(-1.702f * g));
          gated[nf][rr] = (u + 1.f) * (g * sg);
        }
      }
#pragma unroll
      for (int rr = 0; rr < 16; ++rr) {
        float am = fmaxf(fabsf(gated[0][rr]), fabsf(gated[1][rr]));
        am = fmaxf(am, __shfl_xor(am, 2));
        am = fmaxf(am, __shfl_xor(am, 4));
        am = fmaxf(am, __shfl_xor(am, 8));
        am = fmaxf(am, __shfl_xor(am, 16));
        u32 eb = (__float_as_uint(am) >> 23) & 255u;
        float inv = __uint_as_float((256u - eb) << 23);
        int c0 = (am > 0.f) ? quant_code(gated[0][rr], inv) : 0;
        int c1 = (am > 0.f) ? quant_code(gated[1][rr], inv) : 0;
        int b0 = c0 | (__shfl_xor(c0, 2) << 4);   // valid at (lane&3)==0
        int b1 = c1 | (__shfl_xor(c1, 2) << 4);
        int mrow = (rr & 3) + 8 * (rr >> 2) + 4 * hlf;
        int rloc = wm * 64 + mf * 32 + mrow;
        if ((lane & 3) == 0) {
          Glds[rloc * 48 + wn * 16 + (ml >> 2)] = (u8)b0;
          Glds[rloc * 48 + wn * 16 + 8 + (ml >> 2)] = (u8)b1;
          if (rloc < rows && ml == 0)
            gs[(long)(row0 + rloc) * SB + nt * 3 + wn] = (u8)(am > 0.f ? (eb - 2u) : 0u);
        }
      }
    }
    __syncthreads();
    // coalesced 16B stores of the packed tile (128 rows x 48B)
    {
      int row = tid / 3, part = tid % 3;
      uint4 v = *reinterpret_cast<const uint4*>(&Glds[row * 48 + part * 16]);
      *reinterpret_cast<uint4*>(gqp + (long)(row0 + row) * RB + nt * 48 + part * 16) = v;
    }
  } else {
#pragma unroll
    for (int mf = 0; mf < 2; ++mf) {
#pragma unroll
      for (int rr = 0; rr < 16; ++rr) {
        int mrow = (rr & 3) + 8 * (rr >> 2) + 4 * hlf;
        int rloc = wm * 64 + mf * 32 + mrow;
        if (rloc >= rows) continue;
        long rg = row0 + rloc;
#pragma unroll
        for (int nf = 0; nf < 2; ++nf) {
          int hg = nt * BN + wn * 64 + nf * 32 + ml;
          partial[rg * HD + hg] = acc[mf][nf][rr] + bias[e * HD + hg];
        }
      }
    }
  }
}

// ---------------- final combine: out[t] = sum_k rw[t,k] * partial[row(t,k)] ----
__global__ __launch_bounds__(768)
void gather_k(const float* __restrict__ partial, const int* __restrict__ tok2row,
              const float* __restrict__ rw, float* __restrict__ out) {
  int t = blockIdx.x;
  int i = threadIdx.x;
  if (i >= 720) return;            // 720*4 = 2880
  int c = i * 4;
  float4 s = make_float4(0.f, 0.f, 0.f, 0.f);
#pragma unroll
  for (int k = 0; k < 4; ++k) {
    int r = tok2row[t * 4 + k];
    float w = rw[t * 4 + k];
    float4 v = *reinterpret_cast<const float4*>(&partial[(long)r * HD + c]);
    s.x += w * v.x; s.y += w * v.y; s.z += w * v.z; s.w += w * v.w;
  }
  *reinterpret_cast<float4*>(&out[(long)t * HD + c]) = s;
}

// ---------------- launcher ----------------
extern "C" void kernel_launch(void* const* d_in, const int* in_sizes, int n_in,
                              void* d_out, int out_size, void* d_ws, size_t ws_size,
                              hipStream_t stream) {
  (void)in_sizes; (void)n_in; (void)ws_size; (void)out_size;
  const float* x   = (const float*)d_in[0];
  const int* ridx  = (const int*)d_in[1];
  const float* rw  = (const float*)d_in[2];
  const int* guc   = (const int*)d_in[3];
  const int* gus   = (const int*)d_in[4];
  const float* gub = (const float*)d_in[5];
  const int* dnc   = (const int*)d_in[6];
  const int* dns   = (const int*)d_in[7];
  const float* dnb = (const float*)d_in[8];
  float* out = (float*)d_out;
  char* ws = (char*)d_ws;

  // ws layout (~175 MB)
  int* tt_e    = (int*)(ws);
  int* tt_row0 = (int*)(ws + 1024);
  int* tt_rows = (int*)(ws + 2048);
  int* atok    = (int*)(ws + 4096);
  int* tok2row = (int*)(ws + 4096 + MAXPAD * 4);
  size_t off = 65536;
  u8* xqp = (u8*)(ws + off);  off += (size_t)NTOK * RB;       // 1.47 MB
  u8* xs  = (u8*)(ws + off);  off += (size_t)NTOK * SB;       // 98 KB
  u8* gqp = (u8*)(ws + off);  off += (size_t)MAXPAD * RB;     // 7.37 MB
  u8* gs  = (u8*)(ws + off);  off += (size_t)MAXPAD * SB;     // 0.49 MB
  u8* wqg = (u8*)(ws + off);  off += (size_t)NEXP * GUN * RB; // 66.4 MB
  u8* wsg = (u8*)(ws + off);  off += (size_t)NEXP * GUN * SB; // 4.4 MB
  u8* wqd = (u8*)(ws + off);  off += (size_t)NEXP * HD * RB;  // 33.2 MB
  u8* wsd = (u8*)(ws + off);  off += (size_t)NEXP * HD * SB;  // 2.2 MB
  float* partial = (float*)(ws + off); off += (size_t)MAXPAD * HD * 4; // 59 MB

  route_k<<<1, 256, 0, stream>>>(ridx, rw, tt_e, tt_row0, tt_rows, atok, tok2row);
  quant_x_k<<<NTOK, 384, 0, stream>>>(x, xqp, xs);
  repack_k<<<dim3(GUN / 80, 23, NEXP), 320, 0, stream>>>(guc, wqg, GUN);
  srepack_k<<<dim3(GUN / 64, NEXP), 384, 0, stream>>>(gus, wsg, GUN);
  repack_k<<<dim3(HD / 80, 23, NEXP), 320, 0, stream>>>(dnc, wqd, HD);
  srepack_k<<<dim3(HD / 64, NEXP), 384, 0, stream>>>(dns, wsd, HD);
  moe_gemm<true><<<dim3(MAXTILES, 30), 384, 0, stream>>>(
      xqp, xs, wqg, wsg, gub, tt_e, tt_row0, tt_rows, atok, gqp, gs, nullptr);
  moe_gemm<false><<<dim3(MAXTILES, 15), 384, 0, stream>>>(
      gqp, gs, wqd, wsd, dnb, tt_e, tt_row0, tt_rows, atok, nullptr, nullptr, partial);
  gather_k<<<NTOK, 768, 0, stream>>>(partial, tok2row, rw, out);
}

// Round 8
// 608.721 us; speedup vs baseline: 1.1239x; 1.1236x over previous
//
#include <hip/hip_runtime.h>
#include <hip/hip_bf16.h>

typedef unsigned char u8;
typedef unsigned short u16;
typedef unsigned int u32;
typedef int i32x4 __attribute__((ext_vector_type(4)));
typedef int i32x8 __attribute__((ext_vector_type(8)));
typedef float f32x16 __attribute__((ext_vector_type(16)));

#define HD 2880          // H == I == 2880
#define GUN 5760         // 2*I
#define NEXP 8
#define NTOK 1024
#define NASSIGN 4096     // T*K
#define MAXPAD 5120      // padded routed rows (40 tiles x 128)
#define MAXTILES 40
#define SROWS 90         // 2880/32
#define RB 1440          // packed fp4 row bytes (2880/2)
#define SB 96            // padded scale row bytes (90 -> 96)
// tile-linear region sizes
#define ATILE_B 184320   // 90 cs * 128 rows * 16B
#define ASCL_B 11520     // 90 kb * 128 rows
#define BTILE_B 276480   // 45 ks * 384 chunks * 16B
#define BSCL_B 17280     // 90 kb * 192 cols

// ---------------- global -> LDS direct staging (16B per lane) ----------------
__device__ __forceinline__ void gll16(const void* g, void* l) {
  __builtin_amdgcn_global_load_lds(
      (const __attribute__((address_space(1))) u32*)g,
      (__attribute__((address_space(3))) u32*)l, 16, 0, 0);
}

// i32x4 -> i32x8 with UNDEF high half (fp4 MFMA reads only regs 0-3)
__device__ __forceinline__ i32x8 ext8(i32x4 v) {
  return __builtin_shufflevector(v, v, 0, 1, 2, 3, -1, -1, -1, -1);
}

// ---------------- exact mxfp4 code helpers ----------------
__device__ __forceinline__ int quant_code(float v, float inv) {
  float x = v * inv;
  float a = fabsf(x);
  int n;
  if (x > 0.f)
    n = (a > 0.25f) + (a > 0.75f) + (a > 1.25f) + (a > 1.75f) +
        (a > 2.5f)  + (a > 3.5f)  + (a > 5.f);
  else
    n = (a >= 0.25f) + (a >= 0.75f) + (a >= 1.25f) + (a >= 1.75f) +
        (a >= 2.5f)  + (a >= 3.5f)  + (a >= 5.f);
  return x < 0.f ? (8 | n) : n;   // x==0 -> n==0 -> code 0
}

// ---------------- routing ----------------
__global__ __launch_bounds__(256)
void route_k(const int* __restrict__ ridx, const float* __restrict__ rw,
             int* __restrict__ tt_e, int* __restrict__ tt_row0, int* __restrict__ tt_rows,
             int* __restrict__ atok, int* __restrict__ tok2row) {
  __shared__ int cnt[NEXP], cur[NEXP], poff[NEXP];
  int tid = threadIdx.x;
  if (tid < NEXP) { cnt[tid] = 0; cur[tid] = 0; }
  __syncthreads();
  for (int a = tid; a < NASSIGN; a += 256) atomicAdd(&cnt[ridx[a]], 1);
  __syncthreads();
  if (tid == 0) {
    int off = 0, nt = 0;
    for (int e = 0; e < NEXP; ++e) {
      poff[e] = off;
      int cc = cnt[e];
      int ntl = (cc + 127) >> 7;
      for (int i = 0; i < ntl; ++i) {
        int rem = cc - i * 128;
        tt_e[nt] = e; tt_row0[nt] = off + i * 128; tt_rows[nt] = rem < 128 ? rem : 128;
        ++nt;
      }
      off += ntl * 128;
    }
    for (; nt < 64; ++nt) { tt_e[nt] = 0; tt_row0[nt] = 0; tt_rows[nt] = 0; }
  }
  __syncthreads();
  for (int r2 = tid; r2 < MAXPAD; r2 += 256) atok[r2] = 0;
  __syncthreads();
  for (int a = tid; a < NASSIGN; a += 256) {
    int e = ridx[a];
    int p = atomicAdd(&cur[e], 1);
    int r2 = poff[e] + p;
    atok[r2] = a >> 2;
    tok2row[a] = r2;
  }
}

// ---------------- activation quant: x -> packed fp4 + e8m0 scales (row-major) ----
__global__ __launch_bounds__(384)
void quant_x_k(const float* __restrict__ x, u8* __restrict__ xqp, u8* __restrict__ xs) {
  int t = blockIdx.x;
  int tid = threadIdx.x;
  if (tid >= 360) return;       // 360*8 = 2880
  const float* xp = x + (long)t * HD + tid * 8;
  float4 v0 = *reinterpret_cast<const float4*>(xp);
  float4 v1 = *reinterpret_cast<const float4*>(xp + 4);
  float vv[8] = {v0.x, v0.y, v0.z, v0.w, v1.x, v1.y, v1.z, v1.w};
  float am = 0.f;
#pragma unroll
  for (int j = 0; j < 8; ++j) am = fmaxf(am, fabsf(vv[j]));
  am = fmaxf(am, __shfl_xor(am, 1));
  am = fmaxf(am, __shfl_xor(am, 2));
  u32 eb = (__float_as_uint(am) >> 23) & 255u;
  float inv = __uint_as_float((256u - eb) << 23);
  u32 w = 0;
#pragma unroll
  for (int j = 0; j < 8; ++j) {
    u32 c = (am > 0.f) ? (u32)quant_code(vv[j], inv) : 0u;
    w |= c << (4 * j);          // low nibble = even k
  }
  *reinterpret_cast<u32*>(xqp + (long)t * RB + tid * 4) = w;
  if ((tid & 3) == 0)
    xs[(long)t * SB + (tid >> 2)] = (u8)(am > 0.f ? (eb - 2u) : 0u);
}

// ---------------- A gather: routed rows -> tile-linear xqT[mt][cs][row][16B] ----
__global__ __launch_bounds__(384)
void gathx_k(const u8* __restrict__ xqp, const u8* __restrict__ xs,
             const int* __restrict__ atok, u8* __restrict__ xqT, u8* __restrict__ xsT) {
  const int mt = blockIdx.x;
  const int tid = threadIdx.x;
  __shared__ int toks[128];
  if (tid < 128) toks[tid] = atok[mt * 128 + tid];
  __syncthreads();
  u8* base = xqT + (long)mt * ATILE_B;
#pragma unroll
  for (int i = 0; i < 30; ++i) {
    int idx = tid + i * 384;          // 11520 chunks
    int cs = idx >> 7, row = idx & 127;
    uint4 v = *reinterpret_cast<const uint4*>(xqp + (long)toks[row] * RB + cs * 16);
    *reinterpret_cast<uint4*>(base + (long)idx * 16) = v;
  }
  u8* sbase = xsT + (long)mt * ASCL_B;
#pragma unroll
  for (int i = 0; i < 30; ++i) {
    int idx = tid + i * 384;          // 11520 bytes
    int kb = idx >> 7, row = idx & 127;
    sbase[idx] = xs[(long)toks[row] * SB + kb];
  }
}

// ---------------- weight repack (tile-linear): wqT[e][nt][ks][kc][col][16B] ----
// grid: (8*NTILE, 45); thread = one 16B output chunk (32 h codes at fixed f).
__global__ __launch_bounds__(384)
void repackT_k(const int* __restrict__ codes, u8* __restrict__ wqT, int NTILE) {
  const int ND = NTILE * 192;
  const int nt = blockIdx.x % NTILE;
  const int e = blockIdx.x / NTILE;
  const int ks = blockIdx.y;
  const int tid = threadIdx.x;
  const int col = tid % 192, hbh = tid / 192;
  const int kb = ks * 2 + hbh;
  const int f = nt * 192 + col;
  const int* src = codes + ((long)e * HD + kb * 32) * ND + f;
  u32 w[4] = {0, 0, 0, 0};
#pragma unroll
  for (int j = 0; j < 32; ++j) {
    u32 c = (u32)src[(long)j * ND] & 15u;
    w[j >> 3] |= c << ((j & 7) * 4);   // byte j/2: even h low nibble
  }
  *reinterpret_cast<uint4*>(wqT + (((long)blockIdx.x * 45 + ks) * 384 + tid) * 16) =
      make_uint4(w[0], w[1], w[2], w[3]);
}

// ---------------- scale repack (tile-linear): wsT[e][nt][kb(90)][col(192)] u8 ----
__global__ __launch_bounds__(384)
void srepackT_k(const int* __restrict__ scales, u8* __restrict__ wsT, int NTILE) {
  const int ND = NTILE * 192;
  const int nt = blockIdx.x % NTILE;
  const int e = blockIdx.x / NTILE;
  const int tid = threadIdx.x;
  u8* dst = wsT + (long)blockIdx.x * BSCL_B;
#pragma unroll
  for (int i = 0; i < 45; ++i) {
    int idx = tid + i * 384;          // 17280
    int kb = idx / 192, col = idx % 192;
    int s = scales[((long)e * SROWS + kb) * ND + nt * 192 + col];
    dst[idx] = (u8)(s + 115);
  }
}

// ---------------- MX-fp4 MFMA GEMM (tile-linear staging) ----------------
// BM=128, BN=192, BK=64. 384 thr = 6 waves (2m x 3n), wave tile 64x64.
// ALL staging sources are contiguous tile-linear regions -> every
// global_load_lds instruction covers 1KB contiguous. Double-buffered,
// per-wave counted vmcnt ({2,2,2,2,1,1} chunks -> vmcnt(2)/(1)).
template<bool IS_GU>
__global__ __launch_bounds__(384, 3)
void moe_gemm(const u8* __restrict__ Apay, const u8* __restrict__ Ascl,
              const u8* __restrict__ wqT, const u8* __restrict__ wsT,
              const float* __restrict__ bias,
              const int* __restrict__ tt_e, const int* __restrict__ tt_rows,
              u8* __restrict__ gqT, u8* __restrict__ gsT,
              float* __restrict__ partial) {
  constexpr int NTILE = IS_GU ? 30 : 15;
  constexpr int BN = 192;
  constexpr int KS = 45;

  // XCD-chunked bijective swizzle, m-tile fastest (B-panel L2 reuse)
  int nb = gridDim.x * gridDim.y;
  int lin = blockIdx.x + gridDim.x * blockIdx.y;
  int q_ = nb >> 3, r_ = nb & 7;
  int xcd = lin & 7, pos = lin >> 3;
  int L = (xcd < r_ ? xcd * (q_ + 1) : r_ * (q_ + 1) + (xcd - r_) * q_) + pos;
  int mt = L % (int)gridDim.x;
  int nt = L / (int)gridDim.x;

  const int rows = tt_rows[mt];
  if (rows <= 0) return;
  const int e = tt_e[mt];
  const int tid = threadIdx.x;
  const int lane = tid & 63;
  const int wid = tid >> 6;
  const int wm = wid & 1;            // 2 m-waves, span 64
  const int wn = wid >> 1;           // 3 n-waves, span 64
  const int ml = lane & 31;
  const int kc = lane >> 5;

  // A region: [kc(2)][row(128)][16B] = 4KB; B region: [kc(2)][col(192)][16B] = 6KB
  __shared__ __align__(16) u8 Tiles[2][10240];
  __shared__ u8 ASl[ASCL_B];         // [kb][row(128)]
  __shared__ u8 BSl[BSCL_B];         // [kb][col(192)]

  const u8* Abase = Apay + (long)mt * ATILE_B;
  const u8* Bbase = wqT + (long)(e * NTILE + nt) * BTILE_B;

  // ---- staging chunk assignment: 640 chunks = 10 wave-instrs {2,2,2,2,1,1} ----
  const int NI = (wid < 4) ? 2 : 1;
  const int cbase = (wid < 4) ? wid * 128 : 512 + (wid - 4) * 64;
  const u8* csrc[2];
  int cdst[2], cstep[2];
#pragma unroll
  for (int i = 0; i < 2; ++i) {
    int c = cbase + i * 64 + lane;
    if (i < NI) {
      if (c < 256) { csrc[i] = Abase + c * 16; cstep[i] = 4096; }
      else         { csrc[i] = Bbase + (c - 256) * 16; cstep[i] = 6144; }
      cdst[i] = c * 16;
    } else { csrc[i] = Abase; cdst[i] = 0; cstep[i] = 0; }
  }

  auto stage = [&](int buf, int ks) {
#pragma unroll
    for (int i = 0; i < 2; ++i)
      if (i < NI) gll16(csrc[i] + ks * cstep[i], &Tiles[buf][cdst[i]]);
  };

  stage(0, 0);   // prologue: tile 0 in flight

  // ---- one-time scale staging (contiguous copies) ----
  {
    const u8* AsB = Ascl + (long)mt * ASCL_B;
    const u8* BsB = wsT + (long)(e * NTILE + nt) * BSCL_B;
    for (int sc = tid; sc < ASCL_B / 16; sc += 384) gll16(AsB + sc * 16, ASl + sc * 16);
    for (int sc = tid; sc < BSCL_B / 16; sc += 384) gll16(BsB + sc * 16, BSl + sc * 16);
  }

  __syncthreads();   // scales staged + tile 0 drained (compiler full waitcnt)

  f32x16 acc[2][2];
#pragma unroll
  for (int a_ = 0; a_ < 2; ++a_)
#pragma unroll
    for (int b_ = 0; b_ < 2; ++b_)
#pragma unroll
      for (int k_ = 0; k_ < 16; ++k_) acc[a_][b_][k_] = 0.f;

  const int arow0 = wm * 64;
  const int bcol0 = wn * 64;

  for (int ks = 0; ks < KS; ++ks) {
    const int cur = ks & 1;
    if (ks + 1 < KS) {
      stage(cur ^ 1, ks + 1);            // next tile: stays in flight
      if (wid < 4) asm volatile("s_waitcnt vmcnt(2)" ::: "memory");
      else         asm volatile("s_waitcnt vmcnt(1)" ::: "memory");
    } else {
      asm volatile("s_waitcnt vmcnt(0)" ::: "memory");
    }
    __builtin_amdgcn_s_barrier();        // current tile staged on all waves
    __builtin_amdgcn_sched_barrier(0);

    const u8* T = Tiles[cur];
    const int kb = 2 * ks + kc;
    i32x4 af[2], bf[2];
    int sa[2], sb[2];
#pragma unroll
    for (int mf = 0; mf < 2; ++mf) {
      int row = arow0 + mf * 32 + ml;
      af[mf] = *reinterpret_cast<const i32x4*>(&T[(kc * 128 + row) * 16]);
      sa[mf] = (int)ASl[kb * 128 + row];
    }
#pragma unroll
    for (int nf = 0; nf < 2; ++nf) {
      int col = bcol0 + nf * 32 + ml;
      bf[nf] = *reinterpret_cast<const i32x4*>(&T[4096 + (kc * 192 + col) * 16]);
      sb[nf] = (int)BSl[kb * 192 + col];
    }
    __builtin_amdgcn_s_setprio(1);
#pragma unroll
    for (int mf = 0; mf < 2; ++mf)
#pragma unroll
      for (int nf = 0; nf < 2; ++nf)
        acc[mf][nf] = __builtin_amdgcn_mfma_scale_f32_32x32x64_f8f6f4(
            ext8(af[mf]), ext8(bf[nf]), acc[mf][nf], 4, 4, 0, sa[mf], 0, sb[nf]);
    __builtin_amdgcn_s_setprio(0);

    __builtin_amdgcn_sched_barrier(0);
    __builtin_amdgcn_s_barrier();        // reads done before buffer reuse
  }

  // ---- epilogues ----
  const int hlf = lane >> 5;
  if constexpr (IS_GU) {
    u8* Glds = &Tiles[0][0];             // 128 x 48 bytes, overlaid on Tiles
    bool evenl = ((lane & 1) == 0);
#pragma unroll
    for (int mf = 0; mf < 2; ++mf) {
      float gated[2][16];
#pragma unroll
      for (int nf = 0; nf < 2; ++nf) {
        int fgc = nt * BN + wn * 64 + nf * 32 + ml;
        float bown = bias[e * GUN + fgc];
#pragma unroll
        for (int rr = 0; rr < 16; ++rr) {
          float z = acc[mf][nf][rr] + bown;
          float zp = __shfl_xor(z, 1);
          float g = evenl ? z : zp;
          float u = evenl ? zp : z;
          g = fminf(g, 7.f);
          u = fminf(fmaxf(u, -7.f), 7.f);
          float sg = 1.f / (1.f + expf(-1.702f * g));
          gated[nf][rr] = (u + 1.f) * (g * sg);
        }
      }
#pragma unroll
      for (int rr = 0; rr < 16; ++rr) {
        float am = fmaxf(fabsf(gated[0][rr]), fabsf(gated[1][rr]));
        am = fmaxf(am, __shfl_xor(am, 2));
        am = fmaxf(am, __shfl_xor(am, 4));
        am = fmaxf(am, __shfl_xor(am, 8));
        am = fmaxf(am, __shfl_xor(am, 16));
        u32 eb = (__float_as_uint(am) >> 23) & 255u;
        float inv = __uint_as_float((256u - eb) << 23);
        int c0 = (am > 0.f) ? quant_code(gated[0][rr], inv) : 0;
        int c1 = (am > 0.f) ? quant_code(gated[1][rr], inv) : 0;
        int b0 = c0 | (__shfl_xor(c0, 2) << 4);   // valid at (lane&3)==0
        int b1 = c1 | (__shfl_xor(c1, 2) << 4);
        int mrow = (rr & 3) + 8 * (rr >> 2) + 4 * hlf;
        int rloc = wm * 64 + mf * 32 + mrow;
        if ((lane & 3) == 0) {
          Glds[rloc * 48 + wn * 16 + (ml >> 2)] = (u8)b0;
          Glds[rloc * 48 + wn * 16 + 8 + (ml >> 2)] = (u8)b1;
          if (rloc < rows && ml == 0)
            gsT[((long)mt * 90 + nt * 3 + wn) * 128 + rloc] = (u8)(am > 0.f ? (eb - 2u) : 0u);
        }
      }
    }
    __syncthreads();
    // tile-linear gqT store: [cs = nt*3+part][row] contiguous 16B stores
    {
      int part = tid >> 7, row = tid & 127;
      uint4 v = *reinterpret_cast<const uint4*>(&Glds[row * 48 + part * 16]);
      *reinterpret_cast<uint4*>(gqT + ((long)(mt * 90 + nt * 3 + part) * 128 + row) * 16) = v;
    }
  } else {
    const int row0 = mt * 128;           // tiles laid out contiguously
#pragma unroll
    for (int mf = 0; mf < 2; ++mf) {
#pragma unroll
      for (int rr = 0; rr < 16; ++rr) {
        int mrow = (rr & 3) + 8 * (rr >> 2) + 4 * hlf;
        int rloc = wm * 64 + mf * 32 + mrow;
        if (rloc >= rows) continue;
        long rg = row0 + rloc;
#pragma unroll
        for (int nf = 0; nf < 2; ++nf) {
          int hg = nt * BN + wn * 64 + nf * 32 + ml;
          partial[rg * HD + hg] = acc[mf][nf][rr] + bias[e * HD + hg];
        }
      }
    }
  }
}

// ---------------- final combine: out[t] = sum_k rw[t,k] * partial[row(t,k)] ----
__global__ __launch_bounds__(768)
void gather_k(const float* __restrict__ partial, const int* __restrict__ tok2row,
              const float* __restrict__ rw, float* __restrict__ out) {
  int t = blockIdx.x;
  int i = threadIdx.x;
  if (i >= 720) return;            // 720*4 = 2880
  int c = i * 4;
  float4 s = make_float4(0.f, 0.f, 0.f, 0.f);
#pragma unroll
  for (int k = 0; k < 4; ++k) {
    int r = tok2row[t * 4 + k];
    float w = rw[t * 4 + k];
    float4 v = *reinterpret_cast<const float4*>(&partial[(long)r * HD + c]);
    s.x += w * v.x; s.y += w * v.y; s.z += w * v.z; s.w += w * v.w;
  }
  *reinterpret_cast<float4*>(&out[(long)t * HD + c]) = s;
}

// ---------------- launcher ----------------
extern "C" void kernel_launch(void* const* d_in, const int* in_sizes, int n_in,
                              void* d_out, int out_size, void* d_ws, size_t ws_size,
                              hipStream_t stream) {
  (void)in_sizes; (void)n_in; (void)ws_size; (void)out_size;
  const float* x   = (const float*)d_in[0];
  const int* ridx  = (const int*)d_in[1];
  const float* rw  = (const float*)d_in[2];
  const int* guc   = (const int*)d_in[3];
  const int* gus   = (const int*)d_in[4];
  const float* gub = (const float*)d_in[5];
  const int* dnc   = (const int*)d_in[6];
  const int* dns   = (const int*)d_in[7];
  const float* dnb = (const float*)d_in[8];
  float* out = (float*)d_out;
  char* ws = (char*)d_ws;

  // ws layout (~183 MB)
  int* tt_e    = (int*)(ws);
  int* tt_row0 = (int*)(ws + 1024);
  int* tt_rows = (int*)(ws + 2048);
  int* atok    = (int*)(ws + 4096);
  int* tok2row = (int*)(ws + 4096 + MAXPAD * 4);
  size_t off = 65536;
  u8* xqp = (u8*)(ws + off);  off += (size_t)NTOK * RB;            // 1.47 MB
  u8* xs  = (u8*)(ws + off);  off += (size_t)NTOK * SB;            // 98 KB
  u8* xqT = (u8*)(ws + off);  off += (size_t)MAXTILES * ATILE_B;   // 7.37 MB
  u8* xsT = (u8*)(ws + off);  off += (size_t)MAXTILES * ASCL_B;    // 0.46 MB
  u8* gqT = (u8*)(ws + off);  off += (size_t)MAXTILES * ATILE_B;   // 7.37 MB
  u8* gsT = (u8*)(ws + off);  off += (size_t)MAXTILES * ASCL_B;    // 0.46 MB
  u8* wqgT = (u8*)(ws + off); off += (size_t)NEXP * 30 * BTILE_B;  // 66.4 MB
  u8* wsgT = (u8*)(ws + off); off += (size_t)NEXP * 30 * BSCL_B;   // 4.15 MB
  u8* wqdT = (u8*)(ws + off); off += (size_t)NEXP * 15 * BTILE_B;  // 33.2 MB
  u8* wsdT = (u8*)(ws + off); off += (size_t)NEXP * 15 * BSCL_B;   // 2.07 MB
  float* partial = (float*)(ws + off); off += (size_t)MAXPAD * HD * 4; // 59 MB

  route_k<<<1, 256, 0, stream>>>(ridx, rw, tt_e, tt_row0, tt_rows, atok, tok2row);
  quant_x_k<<<NTOK, 384, 0, stream>>>(x, xqp, xs);
  gathx_k<<<MAXTILES, 384, 0, stream>>>(xqp, xs, atok, xqT, xsT);
  repackT_k<<<dim3(NEXP * 30, 45), 384, 0, stream>>>(guc, wqgT, 30);
  srepackT_k<<<NEXP * 30, 384, 0, stream>>>(gus, wsgT, 30);
  repackT_k<<<dim3(NEXP * 15, 45), 384, 0, stream>>>(dnc, wqdT, 15);
  srepackT_k<<<NEXP * 15, 384, 0, stream>>>(dns, wsdT, 15);
  moe_gemm<true><<<dim3(MAXTILES, 30), 384, 0, stream>>>(
      xqT, xsT, wqgT, wsgT, gub, tt_e, tt_rows, gqT, gsT, nullptr);
  moe_gemm<false><<<dim3(MAXTILES, 15), 384, 0, stream>>>(
      gqT, gsT, wqdT, wsdT, dnb, tt_e, tt_rows, nullptr, nullptr, partial);
  gather_k<<<NTOK, 768, 0, stream>>>(partial, tok2row, rw, out);
}

// Round 9
// 526.657 us; speedup vs baseline: 1.2990x; 1.1558x over previous
//
#include <hip/hip_runtime.h>
#include <hip/hip_bf16.h>

typedef unsigned char u8;
typedef unsigned int u32;
typedef unsigned long long u64;
typedef int i32x4 __attribute__((ext_vector_type(4)));
typedef int i32x8 __attribute__((ext_vector_type(8)));
typedef float f32x16 __attribute__((ext_vector_type(16)));

#define HD 2880          // H == I == 2880
#define GUN 5760         // 2*I
#define NEXP 8
#define NTOK 1024
#define NASSIGN 4096     // T*K
#define MAXPAD 5120      // padded routed rows (40 tiles x 128)
#define MAXTILES 40
#define SROWS 90         // 2880/32
#define RB 1440          // packed fp4 row bytes (2880/2)
#define XSB 120          // activation scale row bytes: 15 phases x 8
// per-phase image pieces (BK = 192)
#define APART 13312      // A: pay [kb(6)][row(128)][16B]=12288 + scl [row][8]=1024
#define BPART 19968      // B: pay [kb(6)][col(192)][16B]=18432 + scl [col][8]=1536
#define TILEB 36864      // LDS buffer: APART + BPART + pad  (2304 chunks)

// ---------------- global -> LDS direct staging (16B per lane) ----------------
__device__ __forceinline__ void gll16(const void* g, void* l) {
  __builtin_amdgcn_global_load_lds(
      (const __attribute__((address_space(1))) u32*)g,
      (__attribute__((address_space(3))) u32*)l, 16, 0, 0);
}

// i32x4 -> i32x8 with UNDEF high half (fp4 MFMA reads only regs 0-3)
__device__ __forceinline__ i32x8 ext8(i32x4 v) {
  return __builtin_shufflevector(v, v, 0, 1, 2, 3, -1, -1, -1, -1);
}

// ---------------- exact mxfp4 code helper ----------------
__device__ __forceinline__ int quant_code(float v, float inv) {
  float x = v * inv;
  float a = fabsf(x);
  int n;
  if (x > 0.f)
    n = (a > 0.25f) + (a > 0.75f) + (a > 1.25f) + (a > 1.75f) +
        (a > 2.5f)  + (a > 3.5f)  + (a > 5.f);
  else
    n = (a >= 0.25f) + (a >= 0.75f) + (a >= 1.25f) + (a >= 1.75f) +
        (a >= 2.5f)  + (a >= 3.5f)  + (a >= 5.f);
  return x < 0.f ? (8 | n) : n;   // x==0 -> n==0 -> code 0
}

// ---------------- routing ----------------
__global__ __launch_bounds__(256)
void route_k(const int* __restrict__ ridx, const float* __restrict__ rw,
             int* __restrict__ tt_e, int* __restrict__ tt_row0, int* __restrict__ tt_rows,
             int* __restrict__ atok, int* __restrict__ tok2row) {
  __shared__ int cnt[NEXP], cur[NEXP], poff[NEXP];
  int tid = threadIdx.x;
  if (tid < NEXP) { cnt[tid] = 0; cur[tid] = 0; }
  __syncthreads();
  for (int a = tid; a < NASSIGN; a += 256) atomicAdd(&cnt[ridx[a]], 1);
  __syncthreads();
  if (tid == 0) {
    int off = 0, nt = 0;
    for (int e = 0; e < NEXP; ++e) {
      poff[e] = off;
      int cc = cnt[e];
      int ntl = (cc + 127) >> 7;
      for (int i = 0; i < ntl; ++i) {
        int rem = cc - i * 128;
        tt_e[nt] = e; tt_row0[nt] = off + i * 128; tt_rows[nt] = rem < 128 ? rem : 128;
        ++nt;
      }
      off += ntl * 128;
    }
    for (; nt < 64; ++nt) { tt_e[nt] = 0; tt_row0[nt] = 0; tt_rows[nt] = 0; }
  }
  __syncthreads();
  for (int r2 = tid; r2 < MAXPAD; r2 += 256) atok[r2] = 0;
  __syncthreads();
  for (int a = tid; a < NASSIGN; a += 256) {
    int e = ridx[a];
    int p = atomicAdd(&cur[e], 1);
    int r2 = poff[e] + p;
    atok[r2] = a >> 2;
    tok2row[a] = r2;
  }
}

// ---------------- activation quant: x -> packed fp4 + phase-grouped scales ----
__global__ __launch_bounds__(384)
void quant_x_k(const float* __restrict__ x, u8* __restrict__ xqp, u8* __restrict__ xs) {
  int t = blockIdx.x;
  int tid = threadIdx.x;
  if (tid >= 360) return;       // 360*8 = 2880
  const float* xp = x + (long)t * HD + tid * 8;
  float4 v0 = *reinterpret_cast<const float4*>(xp);
  float4 v1 = *reinterpret_cast<const float4*>(xp + 4);
  float vv[8] = {v0.x, v0.y, v0.z, v0.w, v1.x, v1.y, v1.z, v1.w};
  float am = 0.f;
#pragma unroll
  for (int j = 0; j < 8; ++j) am = fmaxf(am, fabsf(vv[j]));
  am = fmaxf(am, __shfl_xor(am, 1));
  am = fmaxf(am, __shfl_xor(am, 2));
  u32 eb = (__float_as_uint(am) >> 23) & 255u;
  float inv = __uint_as_float((256u - eb) << 23);
  u32 w = 0;
#pragma unroll
  for (int j = 0; j < 8; ++j) {
    u32 c = (am > 0.f) ? (u32)quant_code(vv[j], inv) : 0u;
    w |= c << (4 * j);          // low nibble = even k
  }
  *reinterpret_cast<u32*>(xqp + (long)t * RB + tid * 4) = w;
  if ((tid & 3) == 0) {
    int kb = tid >> 2;          // 0..89
    int p = kb / 6, j = kb % 6;
    xs[(long)t * XSB + p * 8 + j] = (u8)(am > 0.f ? (eb - 2u) : 0u);
  }
}

// ---------------- A gather: routed rows -> per-phase image xqT[mt][p][APART] ----
__global__ __launch_bounds__(384)
void gathx_k(const u8* __restrict__ xqp, const u8* __restrict__ xs,
             const int* __restrict__ atok, u8* __restrict__ xqT) {
  const int mt = blockIdx.x;
  const int tid = threadIdx.x;
  __shared__ int toks[128];
  if (tid < 128) toks[tid] = atok[mt * 128 + tid];
  __syncthreads();
  u8* base = xqT + (long)mt * (15 * APART);
  // payload: 15 phases x 768 chunks; [kb][row][16B]
#pragma unroll
  for (int i = 0; i < 30; ++i) {
    int idx = tid + i * 384;          // 11520
    int p = idx / 768, rem = idx % 768;
    int kb = rem >> 7, row = rem & 127;
    uint4 v = *reinterpret_cast<const uint4*>(xqp + (long)toks[row] * RB + p * 96 + kb * 16);
    *reinterpret_cast<uint4*>(base + (long)p * APART + rem * 16) = v;
  }
  // scales: 15 phases x 128 rows, u64 each
#pragma unroll
  for (int i = 0; i < 5; ++i) {
    int idx = tid + i * 384;          // 1920
    int p = idx >> 7, row = idx & 127;
    u64 v = *reinterpret_cast<const u64*>(xs + (long)toks[row] * XSB + p * 8);
    *reinterpret_cast<u64*>(base + (long)p * APART + 12288 + row * 8) = v;
  }
}

// ---------------- weight repack -> per-phase image wqT[(e,nt)][p][BPART] ----
// grid (NEXP*NTILE, 15); payload: thread does 3 chunks (col fixed, kb=kb0+2i);
// scales: threads 0..191 emit one u64 per col.
__global__ __launch_bounds__(384)
void repackTB_k(const int* __restrict__ codes, const int* __restrict__ scales,
                u8* __restrict__ wqT, int NTILE) {
  const int ND = NTILE * 192;
  const int nt = blockIdx.x % NTILE;
  const int e = blockIdx.x / NTILE;
  const int p = blockIdx.y;
  const int tid = threadIdx.x;
  const int col = tid % 192;
  const int kb0 = tid / 192;
  const int f = nt * 192 + col;
  u8* base = wqT + ((long)blockIdx.x * 15 + p) * BPART;
#pragma unroll
  for (int i = 0; i < 3; ++i) {
    int kb = kb0 + 2 * i;
    const int* src = codes + ((long)e * HD + (p * 6 + kb) * 32) * ND + f;
    u32 w[4] = {0, 0, 0, 0};
#pragma unroll
    for (int j = 0; j < 32; ++j) {
      u32 c = (u32)src[(long)j * ND] & 15u;
      w[j >> 3] |= c << ((j & 7) * 4);
    }
    *reinterpret_cast<uint4*>(base + (kb * 192 + col) * 16) =
        make_uint4(w[0], w[1], w[2], w[3]);
  }
  if (tid < 192) {
    u64 v = 0;
#pragma unroll
    for (int kb = 0; kb < 6; ++kb) {
      u32 s = (u32)(scales[((long)e * SROWS + p * 6 + kb) * ND + f] + 115) & 255u;
      v |= (u64)s << (kb * 8);
    }
    *reinterpret_cast<u64*>(base + 18432 + col * 8) = v;
  }
}

// ---------------- MX-fp4 MFMA GEMM (per-phase image staging, m97 schedule) ----
// BM=128, BN=192, BK=192 -> 15 phases. 384 thr = 6 waves (2m x 3n), wave tile
// 64x64, 12 MFMA/thread/phase. stage(p+1) issued BEFORE compute(p); single
// __syncthreads per phase (vmcnt(0)+lgkmcnt(0)+barrier). Double buffer, 72KB.
template<bool IS_GU>
__global__ __launch_bounds__(384, 3)
void moe_gemm(const u8* __restrict__ At, const u8* __restrict__ Bt,
              const float* __restrict__ bias,
              const int* __restrict__ tt_e, const int* __restrict__ tt_rows,
              u8* __restrict__ gqT, float* __restrict__ partial) {
  constexpr int NTILE = IS_GU ? 30 : 15;
  constexpr int KS = 15;

  // XCD-chunked bijective swizzle, m-tile fastest (B-panel L2 reuse)
  int nb = gridDim.x * gridDim.y;
  int lin = blockIdx.x + gridDim.x * blockIdx.y;
  int q_ = nb >> 3, r_ = nb & 7;
  int xcd = lin & 7, pos = lin >> 3;
  int L = (xcd < r_ ? xcd * (q_ + 1) : r_ * (q_ + 1) + (xcd - r_) * q_) + pos;
  int mt = L % (int)gridDim.x;
  int nt = L / (int)gridDim.x;

  const int rows = tt_rows[mt];
  if (rows <= 0) return;
  const int e = tt_e[mt];
  const int tid = threadIdx.x;
  const int lane = tid & 63;
  const int wid = tid >> 6;
  const int wm = wid & 1;            // 2 m-waves, span 64
  const int wn = wid >> 1;           // 3 n-waves, span 64
  const int ml = lane & 31;
  const int kc = lane >> 5;

  __shared__ __align__(16) u8 Tiles[2][TILEB];

  const u8* Abase = At + (long)mt * (15 * APART);
  const u8* Bbase = Bt + (long)(e * NTILE + nt) * (15 * BPART);

  // 2304 chunks = 6 per thread, uniform; contiguous per wave instruction
  const u8* csrc[6]; int cstep[6], cdst[6];
#pragma unroll
  for (int i = 0; i < 6; ++i) {
    int c = tid + i * 384;
    if (c < 832)       { csrc[i] = Abase + c * 16;          cstep[i] = APART; }
    else if (c < 2080) { csrc[i] = Bbase + (c - 832) * 16;  cstep[i] = BPART; }
    else               { csrc[i] = Abase + (c - 2080) * 16; cstep[i] = APART; }
    cdst[i] = c * 16;
  }

  auto stage = [&](int buf, int p) {
#pragma unroll
    for (int i = 0; i < 6; ++i)
      gll16(csrc[i] + (long)p * cstep[i], &Tiles[buf][cdst[i]]);
  };

  stage(0, 0);   // prologue

  f32x16 acc[2][2];
#pragma unroll
  for (int a_ = 0; a_ < 2; ++a_)
#pragma unroll
    for (int b_ = 0; b_ < 2; ++b_)
#pragma unroll
      for (int k_ = 0; k_ < 16; ++k_) acc[a_][b_][k_] = 0.f;

  const int row0l = wm * 64 + ml;
  const int col0l = wn * 64 + ml;

  __syncthreads();   // tile 0 staged

  for (int p = 0; p < KS; ++p) {
    const int cur = p & 1;
    if (p + 1 < KS) stage(cur ^ 1, p + 1);   // in flight under compute
    const u8* T = Tiles[cur];
    u64 As0 = *reinterpret_cast<const u64*>(&T[12288 + row0l * 8]);
    u64 As1 = *reinterpret_cast<const u64*>(&T[12288 + (row0l + 32) * 8]);
    u64 Bs0 = *reinterpret_cast<const u64*>(&T[31744 + col0l * 8]);
    u64 Bs1 = *reinterpret_cast<const u64*>(&T[31744 + (col0l + 32) * 8]);
#pragma unroll
    for (int t = 0; t < 3; ++t) {
      const int kb = t * 2 + kc;
      const int sh = kb * 8;
      i32x4 af0 = *reinterpret_cast<const i32x4*>(&T[(kb * 128 + row0l) * 16]);
      i32x4 af1 = *reinterpret_cast<const i32x4*>(&T[(kb * 128 + row0l + 32) * 16]);
      i32x4 bf0 = *reinterpret_cast<const i32x4*>(&T[13312 + (kb * 192 + col0l) * 16]);
      i32x4 bf1 = *reinterpret_cast<const i32x4*>(&T[13312 + (kb * 192 + col0l + 32) * 16]);
      int sa0 = (int)((As0 >> sh) & 255), sa1 = (int)((As1 >> sh) & 255);
      int sb0 = (int)((Bs0 >> sh) & 255), sb1 = (int)((Bs1 >> sh) & 255);
      __builtin_amdgcn_s_setprio(1);
      acc[0][0] = __builtin_amdgcn_mfma_scale_f32_32x32x64_f8f6f4(
          ext8(af0), ext8(bf0), acc[0][0], 4, 4, 0, sa0, 0, sb0);
      acc[0][1] = __builtin_amdgcn_mfma_scale_f32_32x32x64_f8f6f4(
          ext8(af0), ext8(bf1), acc[0][1], 4, 4, 0, sa0, 0, sb1);
      acc[1][0] = __builtin_amdgcn_mfma_scale_f32_32x32x64_f8f6f4(
          ext8(af1), ext8(bf0), acc[1][0], 4, 4, 0, sa1, 0, sb0);
      acc[1][1] = __builtin_amdgcn_mfma_scale_f32_32x32x64_f8f6f4(
          ext8(af1), ext8(bf1), acc[1][1], 4, 4, 0, sa1, 0, sb1);
      __builtin_amdgcn_s_setprio(0);
    }
    __syncthreads();   // drain stage(p+1) + all reads of buf cur done
  }

  // ---- epilogues ----
  const int hlf = lane >> 5;
  if constexpr (IS_GU) {
    u8* Glds = &Tiles[0][0];             // 128 x 48 bytes
    const int pdn = nt >> 1;             // DN phase this block's 96 I-cols live in
    const int half = nt & 1;             // which 3-slice half
    bool evenl = ((lane & 1) == 0);
#pragma unroll
    for (int mf = 0; mf < 2; ++mf) {
      float gated[2][16];
#pragma unroll
      for (int nf = 0; nf < 2; ++nf) {
        int fgc = nt * 192 + wn * 64 + nf * 32 + ml;
        float bown = bias[e * GUN + fgc];
#pragma unroll
        for (int rr = 0; rr < 16; ++rr) {
          float z = acc[mf][nf][rr] + bown;
          float zp = __shfl_xor(z, 1);
          float g = evenl ? z : zp;
          float u = evenl ? zp : z;
          g = fminf(g, 7.f);
          u = fminf(fmaxf(u, -7.f), 7.f);
          float sg = 1.f / (1.f + expf(-1.702f * g));
          gated[nf][rr] = (u + 1.f) * (g * sg);
        }
      }
#pragma unroll
      for (int rr = 0; rr < 16; ++rr) {
        float am = fmaxf(fabsf(gated[0][rr]), fabsf(gated[1][rr]));
        am = fmaxf(am, __shfl_xor(am, 2));
        am = fmaxf(am, __shfl_xor(am, 4));
        am = fmaxf(am, __shfl_xor(am, 8));
        am = fmaxf(am, __shfl_xor(am, 16));
        u32 eb = (__float_as_uint(am) >> 23) & 255u;
        float inv = __uint_as_float((256u - eb) << 23);
        int c0 = (am > 0.f) ? quant_code(gated[0][rr], inv) : 0;
        int c1 = (am > 0.f) ? quant_code(gated[1][rr], inv) : 0;
        int b0 = c0 | (__shfl_xor(c0, 2) << 4);   // valid at (lane&3)==0
        int b1 = c1 | (__shfl_xor(c1, 2) << 4);
        int mrow = (rr & 3) + 8 * (rr >> 2) + 4 * hlf;
        int rloc = wm * 64 + mf * 32 + mrow;
        if ((lane & 3) == 0) {
          Glds[rloc * 48 + wn * 16 + (ml >> 2)] = (u8)b0;
          Glds[rloc * 48 + wn * 16 + 8 + (ml >> 2)] = (u8)b1;
          if (rloc < rows && ml == 0)
            gqT[((long)mt * 15 + pdn) * APART + 12288 + rloc * 8 + half * 3 + wn] =
                (u8)(am > 0.f ? (eb - 2u) : 0u);
        }
      }
    }
    __syncthreads();
    // payload: 3 slices x 128 rows x 16B into DN per-phase image
    {
      int part = tid >> 7, row = tid & 127;
      uint4 v = *reinterpret_cast<const uint4*>(&Glds[row * 48 + part * 16]);
      *reinterpret_cast<uint4*>(gqT + ((long)mt * 15 + pdn) * APART +
                                ((half * 3 + part) * 128 + row) * 16) = v;
    }
  } else {
    const int row0 = mt * 128;
#pragma unroll
    for (int mf = 0; mf < 2; ++mf) {
#pragma unroll
      for (int rr = 0; rr < 16; ++rr) {
        int mrow = (rr & 3) + 8 * (rr >> 2) + 4 * hlf;
        int rloc = wm * 64 + mf * 32 + mrow;
        if (rloc >= rows) continue;
        long rg = row0 + rloc;
#pragma unroll
        for (int nf = 0; nf < 2; ++nf) {
          int hg = nt * 192 + wn * 64 + nf * 32 + ml;
          partial[rg * HD + hg] = acc[mf][nf][rr] + bias[e * HD + hg];
        }
      }
    }
  }
}

// ---------------- final combine: out[t] = sum_k rw[t,k] * partial[row(t,k)] ----
__global__ __launch_bounds__(768)
void gather_k(const float* __restrict__ partial, const int* __restrict__ tok2row,
              const float* __restrict__ rw, float* __restrict__ out) {
  int t = blockIdx.x;
  int i = threadIdx.x;
  if (i >= 720) return;            // 720*4 = 2880
  int c = i * 4;
  float4 s = make_float4(0.f, 0.f, 0.f, 0.f);
#pragma unroll
  for (int k = 0; k < 4; ++k) {
    int r = tok2row[t * 4 + k];
    float w = rw[t * 4 + k];
    float4 v = *reinterpret_cast<const float4*>(&partial[(long)r * HD + c]);
    s.x += w * v.x; s.y += w * v.y; s.z += w * v.z; s.w += w * v.w;
  }
  *reinterpret_cast<float4*>(&out[(long)t * HD + c]) = s;
}

// ---------------- launcher ----------------
extern "C" void kernel_launch(void* const* d_in, const int* in_sizes, int n_in,
                              void* d_out, int out_size, void* d_ws, size_t ws_size,
                              hipStream_t stream) {
  (void)in_sizes; (void)n_in; (void)ws_size; (void)out_size;
  const float* x   = (const float*)d_in[0];
  const int* ridx  = (const int*)d_in[1];
  const float* rw  = (const float*)d_in[2];
  const int* guc   = (const int*)d_in[3];
  const int* gus   = (const int*)d_in[4];
  const float* gub = (const float*)d_in[5];
  const int* dnc   = (const int*)d_in[6];
  const int* dns   = (const int*)d_in[7];
  const float* dnb = (const float*)d_in[8];
  float* out = (float*)d_out;
  char* ws = (char*)d_ws;

  // ws layout (~185 MB)
  int* tt_e    = (int*)(ws);
  int* tt_row0 = (int*)(ws + 1024);
  int* tt_rows = (int*)(ws + 2048);
  int* atok    = (int*)(ws + 4096);
  int* tok2row = (int*)(ws + 4096 + MAXPAD * 4);
  size_t off = 65536;
  u8* xqp = (u8*)(ws + off);  off += (size_t)NTOK * RB;               // 1.47 MB
  u8* xs  = (u8*)(ws + off);  off += (size_t)NTOK * XSB;              // 123 KB
  u8* xqT = (u8*)(ws + off);  off += (size_t)MAXTILES * 15 * APART;   // 7.99 MB
  u8* gqT = (u8*)(ws + off);  off += (size_t)MAXTILES * 15 * APART;   // 7.99 MB
  u8* wqgT = (u8*)(ws + off); off += (size_t)NEXP * 30 * 15 * BPART;  // 71.9 MB
  u8* wqdT = (u8*)(ws + off); off += (size_t)NEXP * 15 * 15 * BPART;  // 35.9 MB
  float* partial = (float*)(ws + off); off += (size_t)MAXPAD * HD * 4; // 59 MB

  route_k<<<1, 256, 0, stream>>>(ridx, rw, tt_e, tt_row0, tt_rows, atok, tok2row);
  quant_x_k<<<NTOK, 384, 0, stream>>>(x, xqp, xs);
  gathx_k<<<MAXTILES, 384, 0, stream>>>(xqp, xs, atok, xqT);
  repackTB_k<<<dim3(NEXP * 30, 15), 384, 0, stream>>>(guc, gus, wqgT, 30);
  repackTB_k<<<dim3(NEXP * 15, 15), 384, 0, stream>>>(dnc, dns, wqdT, 15);
  moe_gemm<true><<<dim3(MAXTILES, 30), 384, 0, stream>>>(
      xqT, wqgT, gub, tt_e, tt_rows, gqT, nullptr);
  moe_gemm<false><<<dim3(MAXTILES, 15), 384, 0, stream>>>(
      gqT, wqdT, dnb, tt_e, tt_rows, nullptr, partial);
  gather_k<<<NTOK, 768, 0, stream>>>(partial, tok2row, rw, out);
}